// Round 12
// baseline (45.401 us; speedup 1.0000x reference)
//
#include <hip/hip_runtime.h>

// NeRF backbone builder — R9 proven structure (1 wave/chain, S=8, step3 math,
// scan, transform-pass3) + two changes driven by R10/R11 counters:
//  (1) half-LDS staging (9216B) -> 16 blocks/CU (occupancy 2x). Halves align
//      with lanes 0-31 / 32-63 via R11's shifted-window trick (neighbor row
//      by shfl_up; single-wave barriers are cheap).
//  (2) stage as 18 ds_write_b128 from NAMED registers (no f[] array — R11's
//      scratch-demotion lesson) instead of 72 scalar swizzled writes.

struct V3 { float x, y, z; };

__device__ __forceinline__ V3 vsub(V3 a, V3 b){ return {a.x-b.x, a.y-b.y, a.z-b.z}; }
__device__ __forceinline__ V3 vcross(V3 a, V3 b){
    return {a.y*b.z - a.z*b.y, a.z*b.x - a.x*b.z, a.x*b.y - a.y*b.x};
}
__device__ __forceinline__ float vdot(V3 a, V3 b){ return a.x*b.x + a.y*b.y + a.z*b.z; }
__device__ __forceinline__ V3 vunit(V3 a){
    float r = rsqrtf(vdot(a,a));
    return {a.x*r, a.y*r, a.z*r};
}

struct Xform { V3 c0, c1, c2, t; };  // p' = c0*px + c1*py + c2*pz + t

__device__ __forceinline__ V3 xrot(const Xform& X, V3 p){
    return { X.c0.x*p.x + X.c1.x*p.y + X.c2.x*p.z,
             X.c0.y*p.x + X.c1.y*p.y + X.c2.y*p.z,
             X.c0.z*p.x + X.c1.z*p.y + X.c2.z*p.z };
}
__device__ __forceinline__ V3 xapply(const Xform& X, V3 p){
    V3 r = xrot(X, p);
    return { r.x + X.t.x, r.y + X.t.y, r.z + X.t.z };
}
__device__ __forceinline__ Xform xcompose(const Xform& A, const Xform& B){ // A∘B (B first)
    Xform R;
    R.c0 = xrot(A, B.c0);
    R.c1 = xrot(A, B.c1);
    R.c2 = xrot(A, B.c2);
    R.t  = xapply(A, B.t);
    return R;
}

__device__ __forceinline__ Xform frame_of(V3 A, V3 B, V3 C){
    V3 bc  = vunit(vsub(C, B));
    V3 n   = vunit(vcross(vsub(B, A), bc));
    V3 nbc = vcross(n, bc);
    return { bc, nbc, n, C };
}

__device__ __forceinline__ Xform shfl_up_xf(const Xform& X, int d){
    Xform R;
    R.c0.x = __shfl_up(X.c0.x, d); R.c0.y = __shfl_up(X.c0.y, d); R.c0.z = __shfl_up(X.c0.z, d);
    R.c1.x = __shfl_up(X.c1.x, d); R.c1.y = __shfl_up(X.c1.y, d); R.c1.z = __shfl_up(X.c1.z, d);
    R.c2.x = __shfl_up(X.c2.x, d); R.c2.y = __shfl_up(X.c2.y, d); R.c2.z = __shfl_up(X.c2.z, d);
    R.t.x  = __shfl_up(X.t.x,  d); R.t.y  = __shfl_up(X.t.y,  d); R.t.z  = __shfl_up(X.t.z,  d);
    return R;
}

// Bond constants: d0 = -L*cos(theta), Ls = L*sin(theta)
#define D0_CN   0.56630847f
#define LS_CN   1.21445243f
#define D0_NCA  0.75195559f
#define LS_NCA  1.25146426f
#define D0_CAC  0.50137496f
#define LS_CAC  1.45609861f

// Canonical incoming triple in its own frame (HW-validated R2..R10)
#define A0X (-2.0153295f)
#define A0Y ( 1.3804571f)

// World init triple
#define NIX 17.047f
#define NIY 14.099f
#define NIZ  3.625f
#define CAX 16.967f
#define CAY 12.784f
#define CAZ  4.338f
#define CIX 15.685f
#define CIY 12.755f
#define CIZ  5.133f

__device__ __forceinline__ V3 place_dihedral(V3 a, V3 b, V3 c,
                                             float d0, float Ls, float tor){
    V3 ab = vsub(b, a);
    V3 bc = vunit(vsub(c, b));
    V3 n  = vunit(vcross(ab, bc));
    V3 nbc = vcross(n, bc);
    float sn, cs;
    __sincosf(tor, &sn, &cs);
    float d1 = Ls * cs;
    float d2 = Ls * sn;
    return { c.x + d0*bc.x + d1*nbc.x + d2*n.x,
             c.y + d0*bc.y + d1*nbc.y + d2*n.y,
             c.z + d0*bc.z + d1*nbc.z + d2*n.z };
}

__device__ __forceinline__ void step3(V3& A, V3& B, V3& C,
                                      float tpsi, float tome, float tphi){
    V3 dn  = place_dihedral(A, B, C,  D0_CN,  LS_CN,  tpsi);
    V3 dca = place_dihedral(B, C, dn, D0_NCA, LS_NCA, tome);
    V3 dc  = place_dihedral(C, dn, dca, D0_CAC, LS_CAC, tphi);
    A = dn; B = dca; C = dc;
}

// float4-granular XOR swizzle (involution) — same mapping as R6's float-level
// swz restricted to 16B blocks; used identically on write and read side.
__device__ __forceinline__ void put4(float4* lds4, int p, float4 v){
    lds4[p ^ ((p >> 6) & 7)] = v;
}

// Stage 4 rows (36 floats = 9 float4) starting at float4 index p.
// Row layout: (A.x A.y A.z B.x B.y B.z C.x C.y C.z).
__device__ __forceinline__ void stage36(float4* lds4, int p,
    V3 aA, V3 aB, V3 aC, V3 bA, V3 bB, V3 bC,
    V3 cA, V3 cB, V3 cC, V3 dA, V3 dB, V3 dC){
    put4(lds4, p+0, make_float4(aA.x, aA.y, aA.z, aB.x));
    put4(lds4, p+1, make_float4(aB.y, aB.z, aC.x, aC.y));
    put4(lds4, p+2, make_float4(aC.z, bA.x, bA.y, bA.z));
    put4(lds4, p+3, make_float4(bB.x, bB.y, bB.z, bC.x));
    put4(lds4, p+4, make_float4(bC.y, bC.z, cA.x, cA.y));
    put4(lds4, p+5, make_float4(cA.z, cB.x, cB.y, cB.z));
    put4(lds4, p+6, make_float4(cC.x, cC.y, cC.z, dA.x));
    put4(lds4, p+7, make_float4(dA.y, dA.z, dB.x, dB.y));
    put4(lds4, p+8, make_float4(dB.z, dC.x, dC.y, dC.z));
}

// ---- Fused kernel: one wave per chain, half-LDS staging ----
__global__ __launch_bounds__(64, 4)
void nerf_half(const float* __restrict__ phi,
               const float* __restrict__ psi,
               const float* __restrict__ omega,
               float* __restrict__ out,
               int steps){
    const int L = 512;
    int b = blockIdx.x;
    int k = threadIdx.x;              // chunk id 0..63
    int s0 = k * 8;

    __shared__ float4 lds4[576];      // 9216 B = half chain

    const float* pphi = phi   + (size_t)b * L;
    const float* ppsi = psi   + (size_t)b * L;
    const float* pome = omega + (size_t)b * L;

    float4 ps0 = ((const float4*)(ppsi + s0))[0];
    float4 ps1 = ((const float4*)(ppsi + s0))[1];
    float4 om0 = ((const float4*)(pome + s0))[0];
    float4 om1 = ((const float4*)(pome + s0))[1];
    float4 ph0 = ((const float4*)(pphi + s0))[0];
    float4 ph1 = ((const float4*)(pphi + s0))[1];
    float phi8 = __shfl_down(ph0.x, 1);   // phi[s0+8] from lane k+1 (unused at k=63)

    float tpsi[8] = {ps0.x, ps0.y, ps0.z, ps0.w, ps1.x, ps1.y, ps1.z, ps1.w};
    float tome[8] = {om0.x, om0.y, om0.z, om0.w, om1.x, om1.y, om1.z, om1.w};
    float tphi[8] = {ph0.y, ph0.z, ph0.w, ph1.x, ph1.y, ph1.z, ph1.w, phi8};

    // Pass 1: local chunk atoms in registers (R9-proven).
    V3 A, Bv, C;
    if (k == 0){
        A = {NIX, NIY, NIZ}; Bv = {CAX, CAY, CAZ}; C = {CIX, CIY, CIZ};
    } else {
        A = {A0X, A0Y, 0.f}; Bv = {-1.54f, 0.f, 0.f}; C = {0.f, 0.f, 0.f};
    }
    V3 locA[8], locB[8], locC[8];
    #pragma unroll
    for (int s = 0; s < 8; ++s){
        if (s0 + s < steps)
            step3(A, Bv, C, tpsi[s], tome[s], tphi[s]);
        locA[s] = A; locB[s] = Bv; locC[s] = C;   // k63 s7: dup, never staged
    }
    Xform V = frame_of(A, Bv, C);

    // Pass 2: in-wave inclusive scan (proven R2..R10).
    #pragma unroll
    for (int d = 1; d < 64; d <<= 1){
        Xform Pr = shfl_up_xf(V, d);
        if (k >= d) V = xcompose(Pr, V);
    }
    Xform Wp = shfl_up_xf(V, 1);      // W_{k-1} at lane k (lane 0 unused)

    // Pass 3: transform local atoms to world IN PLACE (R9-proven math).
    if (k != 0){
        #pragma unroll
        for (int s = 0; s < 8; ++s){
            locA[s] = xapply(Wp, locA[s]);
            locB[s] = xapply(Wp, locB[s]);
            locC[s] = xapply(Wp, locC[s]);
        }
    }

    // Neighbor row (shifted window): lane k's output rows are 8k..8k+7 =
    // lane k-1's last row (global row 8k) + own steps s=0..6 (rows 8k+1..8k+7).
    V3 nA, nB, nC;
    nA.x = __shfl_up(locA[7].x, 1); nA.y = __shfl_up(locA[7].y, 1); nA.z = __shfl_up(locA[7].z, 1);
    nB.x = __shfl_up(locB[7].x, 1); nB.y = __shfl_up(locB[7].y, 1); nB.z = __shfl_up(locB[7].z, 1);
    nC.x = __shfl_up(locC[7].x, 1); nC.y = __shfl_up(locC[7].y, 1); nC.z = __shfl_up(locC[7].z, 1);
    if (k == 0){                       // row 0 = init triple
        nA = {NIX, NIY, NIZ}; nB = {CAX, CAY, CAZ}; nC = {CIX, CIY, CIZ};
    }

    int m = k & 31;                    // lane offset within half
    int p0 = 18 * m;                   // float4 base within half buffer
    float4* o4 = (float4*)(out + (size_t)b * 4608u);

    // Half 0: lanes 0..31 stage rows 0..255, whole wave flushes.
    if (k < 32){
        stage36(lds4, p0,     nA, nB, nC, locA[0], locB[0], locC[0],
                              locA[1], locB[1], locC[1], locA[2], locB[2], locC[2]);
        stage36(lds4, p0 + 9, locA[3], locB[3], locC[3], locA[4], locB[4], locC[4],
                              locA[5], locB[5], locC[5], locA[6], locB[6], locC[6]);
    }
    __syncthreads();
    #pragma unroll
    for (int i = 0; i < 9; ++i){
        int q = i * 64 + k;
        o4[q] = lds4[q ^ ((q >> 6) & 7)];
    }
    __syncthreads();

    // Half 1: lanes 32..63 stage rows 256..511, whole wave flushes.
    if (k >= 32){
        stage36(lds4, p0,     nA, nB, nC, locA[0], locB[0], locC[0],
                              locA[1], locB[1], locC[1], locA[2], locB[2], locC[2]);
        stage36(lds4, p0 + 9, locA[3], locB[3], locC[3], locA[4], locB[4], locC[4],
                              locA[5], locB[5], locC[5], locA[6], locB[6], locC[6]);
    }
    __syncthreads();
    #pragma unroll
    for (int i = 0; i < 9; ++i){
        int q = i * 64 + k;
        o4[576 + q] = lds4[q ^ ((q >> 6) & 7)];
    }
}

// ---- Fallback: sequential one-thread-per-chain (general sizes) ----
__global__ void nerf_seq_kernel(const float* __restrict__ phi,
                                const float* __restrict__ psi,
                                const float* __restrict__ omega,
                                float* __restrict__ out,
                                int B, int L, int steps){
    int b = blockIdx.x * blockDim.x + threadIdx.x;
    if (b >= B) return;
    V3 A  = {NIX, NIY, NIZ};
    V3 Bv = {CAX, CAY, CAZ};
    V3 C  = {CIX, CIY, CIZ};
    float* o = out + (size_t)b * 9u * (size_t)(steps + 1);
    o[0]=A.x;  o[1]=A.y;  o[2]=A.z;
    o[3]=Bv.x; o[4]=Bv.y; o[5]=Bv.z;
    o[6]=C.x;  o[7]=C.y;  o[8]=C.z;
    const float* pphi = phi   + (size_t)b * L;
    const float* ppsi = psi   + (size_t)b * L;
    const float* pome = omega + (size_t)b * L;
    for (int s = 0; s < steps; ++s){
        step3(A, Bv, C, ppsi[s], pome[s], pphi[s + 1]);
        float* os = o + 9u * (size_t)(s + 1);
        os[0]=A.x;  os[1]=A.y;  os[2]=A.z;
        os[3]=Bv.x; os[4]=Bv.y; os[5]=Bv.z;
        os[6]=C.x;  os[7]=C.y;  os[8]=C.z;
    }
}

extern "C" void kernel_launch(void* const* d_in, const int* in_sizes, int n_in,
                              void* d_out, int out_size, void* d_ws, size_t ws_size,
                              hipStream_t stream) {
    const float* phi   = (const float*)d_in[0];
    const float* psi   = (const float*)d_in[1];
    const float* omega = (const float*)d_in[2];
    float* out = (float*)d_out;

    const int L = 512;
    int B = in_sizes[0] / L;
    int steps = out_size / (9 * B) - 1;

    if (steps == 511 && in_sizes[0] == B * 512) {
        nerf_half<<<B, 64, 0, stream>>>(phi, psi, omega, out, steps);
    } else {
        int block = 64;
        int grid = (B + block - 1) / block;
        nerf_seq_kernel<<<grid, block, 0, stream>>>(phi, psi, omega, out, B, L, steps);
    }
}

// Round 13
// 37.600 us; speedup vs baseline: 1.2075x; 1.2075x over previous
//
#include <hip/hip_runtime.h>

// NeRF backbone builder — R10 proven base (2 waves/chain, S=4, step3 math,
// per-wave scan + wc handoff, transform-pass3) + direct global stores from
// NAMED registers (shifted window, 9 aligned float4/thread). No staging LDS,
// no flush barrier. R11/R12 lesson applied: zero runtime-indexed arrays.

struct V3 { float x, y, z; };

__device__ __forceinline__ V3 vsub(V3 a, V3 b){ return {a.x-b.x, a.y-b.y, a.z-b.z}; }
__device__ __forceinline__ V3 vcross(V3 a, V3 b){
    return {a.y*b.z - a.z*b.y, a.z*b.x - a.x*b.z, a.x*b.y - a.y*b.x};
}
__device__ __forceinline__ float vdot(V3 a, V3 b){ return a.x*b.x + a.y*b.y + a.z*b.z; }
__device__ __forceinline__ V3 vunit(V3 a){
    float r = rsqrtf(vdot(a,a));
    return {a.x*r, a.y*r, a.z*r};
}

struct Xform { V3 c0, c1, c2, t; };  // p' = c0*px + c1*py + c2*pz + t

__device__ __forceinline__ V3 xrot(const Xform& X, V3 p){
    return { X.c0.x*p.x + X.c1.x*p.y + X.c2.x*p.z,
             X.c0.y*p.x + X.c1.y*p.y + X.c2.y*p.z,
             X.c0.z*p.x + X.c1.z*p.y + X.c2.z*p.z };
}
__device__ __forceinline__ V3 xapply(const Xform& X, V3 p){
    V3 r = xrot(X, p);
    return { r.x + X.t.x, r.y + X.t.y, r.z + X.t.z };
}
__device__ __forceinline__ Xform xcompose(const Xform& A, const Xform& B){ // A∘B (B first)
    Xform R;
    R.c0 = xrot(A, B.c0);
    R.c1 = xrot(A, B.c1);
    R.c2 = xrot(A, B.c2);
    R.t  = xapply(A, B.t);
    return R;
}

__device__ __forceinline__ Xform frame_of(V3 A, V3 B, V3 C){
    V3 bc  = vunit(vsub(C, B));
    V3 n   = vunit(vcross(vsub(B, A), bc));
    V3 nbc = vcross(n, bc);
    return { bc, nbc, n, C };
}

__device__ __forceinline__ Xform shfl_up_xf(const Xform& X, int d){
    Xform R;
    R.c0.x = __shfl_up(X.c0.x, d); R.c0.y = __shfl_up(X.c0.y, d); R.c0.z = __shfl_up(X.c0.z, d);
    R.c1.x = __shfl_up(X.c1.x, d); R.c1.y = __shfl_up(X.c1.y, d); R.c1.z = __shfl_up(X.c1.z, d);
    R.c2.x = __shfl_up(X.c2.x, d); R.c2.y = __shfl_up(X.c2.y, d); R.c2.z = __shfl_up(X.c2.z, d);
    R.t.x  = __shfl_up(X.t.x,  d); R.t.y  = __shfl_up(X.t.y,  d); R.t.z  = __shfl_up(X.t.z,  d);
    return R;
}

// Bond constants: d0 = -L*cos(theta), Ls = L*sin(theta)
#define D0_CN   0.56630847f
#define LS_CN   1.21445243f
#define D0_NCA  0.75195559f
#define LS_NCA  1.25146426f
#define D0_CAC  0.50137496f
#define LS_CAC  1.45609861f

// Canonical incoming triple in its own frame (HW-validated R2..R10)
#define A0X (-2.0153295f)
#define A0Y ( 1.3804571f)

// World init triple
#define NIX 17.047f
#define NIY 14.099f
#define NIZ  3.625f
#define CAX 16.967f
#define CAY 12.784f
#define CAZ  4.338f
#define CIX 15.685f
#define CIY 12.755f
#define CIZ  5.133f

__device__ __forceinline__ V3 place_dihedral(V3 a, V3 b, V3 c,
                                             float d0, float Ls, float tor){
    V3 ab = vsub(b, a);
    V3 bc = vunit(vsub(c, b));
    V3 n  = vunit(vcross(ab, bc));
    V3 nbc = vcross(n, bc);
    float sn, cs;
    __sincosf(tor, &sn, &cs);
    float d1 = Ls * cs;
    float d2 = Ls * sn;
    return { c.x + d0*bc.x + d1*nbc.x + d2*n.x,
             c.y + d0*bc.y + d1*nbc.y + d2*n.y,
             c.z + d0*bc.z + d1*nbc.z + d2*n.z };
}

__device__ __forceinline__ void step3(V3& A, V3& B, V3& C,
                                      float tpsi, float tome, float tphi){
    V3 dn  = place_dihedral(A, B, C,  D0_CN,  LS_CN,  tpsi);
    V3 dca = place_dihedral(B, C, dn, D0_NCA, LS_NCA, tome);
    V3 dc  = place_dihedral(C, dn, dca, D0_CAC, LS_CAC, tphi);
    A = dn; B = dca; C = dc;
}

// ---- Fused kernel (steps==511, L==512): 2 waves/chain, S=4, direct stores ----
__global__ __launch_bounds__(128, 4)
void nerf_direct2(const float* __restrict__ phi,
                  const float* __restrict__ psi,
                  const float* __restrict__ omega,
                  float* __restrict__ out,
                  int steps){
    const int L = 512;
    int b   = blockIdx.x;
    int tid = threadIdx.x;
    int w   = tid >> 6;                 // wave 0 / 1
    int k   = tid & 63;                 // lane in wave

    __shared__ float wc[12];            // wave0 total transform handoff only

    const float* pphi = phi   + (size_t)b * L;
    const float* ppsi = psi   + (size_t)b * L;
    const float* pome = omega + (size_t)b * L;

    int s0 = tid << 2;                  // first step of this chunk

    float4 ps = *(const float4*)(ppsi + s0);
    float4 om = *(const float4*)(pome + s0);
    float4 ph = *(const float4*)(pphi + s0);
    float phn = __shfl_down(ph.x, 1);               // phi[s0+4] from lane k+1
    if (k == 63) phn = (w == 0) ? pphi[256] : 0.f;  // w1 k63 s3 is masked anyway
    float tpsi[4] = {ps.x, ps.y, ps.z, ps.w};
    float tome[4] = {om.x, om.y, om.z, om.w};
    float tphi[4] = {ph.y, ph.z, ph.w, phn};

    // ---- pass 1: chunk atoms in LOCAL coords (statically unrolled regs) ----
    V3 A, Bv, C;
    if (tid == 0){
        A = {NIX, NIY, NIZ}; Bv = {CAX, CAY, CAZ}; C = {CIX, CIY, CIZ};
    } else {
        A = {A0X, A0Y, 0.f}; Bv = {-1.54f, 0.f, 0.f}; C = {0.f, 0.f, 0.f};
    }
    V3 locA[4], locB[4], locC[4];
    #pragma unroll
    for (int s = 0; s < 4; ++s){
        if (s0 + s < steps)
            step3(A, Bv, C, tpsi[s], tome[s], tphi[s]);
        locA[s] = A; locB[s] = Bv; locC[s] = C;   // masked slots: dup, unused
    }
    Xform V = frame_of(A, Bv, C);

    // ---- per-wave inclusive scan (proven R8/R10) ----
    #pragma unroll
    for (int d = 1; d < 64; d <<= 1){
        Xform Pr = shfl_up_xf(V, d);
        if (k >= d) V = xcompose(Pr, V);
    }
    Xform Vp = shfl_up_xf(V, 1);        // wave-local prefix through lane k-1

    if (w == 0 && k == 63){             // publish wave0 total (through step 255)
        wc[0]=V.c0.x; wc[1]=V.c0.y; wc[2]=V.c0.z;
        wc[3]=V.c1.x; wc[4]=V.c1.y; wc[5]=V.c1.z;
        wc[6]=V.c2.x; wc[7]=V.c2.y; wc[8]=V.c2.z;
        wc[9]=V.t.x;  wc[10]=V.t.y; wc[11]=V.t.z;
    }
    __syncthreads();

    Xform Wc;
    Wc.c0 = {wc[0],wc[1],wc[2]};
    Wc.c1 = {wc[3],wc[4],wc[5]};
    Wc.c2 = {wc[6],wc[7],wc[8]};
    Wc.t  = {wc[9],wc[10],wc[11]};

    // ---- pass 3: transform local atoms to world IN PLACE (proven R9/R10) ----
    if (tid != 0){
        Xform W;
        if (w == 0)      W = Vp;
        else if (k == 0) W = Wc;
        else             W = xcompose(Wc, Vp);
        #pragma unroll
        for (int s = 0; s < 4; ++s){
            locA[s] = xapply(W, locA[s]);
            locB[s] = xapply(W, locB[s]);
            locC[s] = xapply(W, locC[s]);
        }
    }

    // ---- neighbor row (shifted window): row 4*tid ----
    V3 nA, nB, nC;
    nA.x = __shfl_up(locA[3].x, 1); nA.y = __shfl_up(locA[3].y, 1); nA.z = __shfl_up(locA[3].z, 1);
    nB.x = __shfl_up(locB[3].x, 1); nB.y = __shfl_up(locB[3].y, 1); nB.z = __shfl_up(locB[3].z, 1);
    nC.x = __shfl_up(locC[3].x, 1); nC.y = __shfl_up(locC[3].y, 1); nC.z = __shfl_up(locC[3].z, 1);
    if (tid == 0){                      // row 0 = init triple
        nA = {NIX, NIY, NIZ}; nB = {CAX, CAY, CAZ}; nC = {CIX, CIY, CIZ};
    } else if (k == 0){                 // tid==64: row 256 from Wc (R8-proven math)
        nA = xapply(Wc, {A0X, A0Y, 0.f});
        nB = xapply(Wc, {-1.54f, 0.f, 0.f});
        nC = Wc.t;
    }

    // ---- direct stores: rows 4tid..4tid+3 = 9 aligned float4, named regs ----
    float4* o4 = (float4*)(out + (size_t)b * 4608u) + 9 * tid;
    o4[0] = make_float4(nA.x, nA.y, nA.z, nB.x);
    o4[1] = make_float4(nB.y, nB.z, nC.x, nC.y);
    o4[2] = make_float4(nC.z, locA[0].x, locA[0].y, locA[0].z);
    o4[3] = make_float4(locB[0].x, locB[0].y, locB[0].z, locC[0].x);
    o4[4] = make_float4(locC[0].y, locC[0].z, locA[1].x, locA[1].y);
    o4[5] = make_float4(locA[1].z, locB[1].x, locB[1].y, locB[1].z);
    o4[6] = make_float4(locC[1].x, locC[1].y, locC[1].z, locA[2].x);
    o4[7] = make_float4(locA[2].y, locA[2].z, locB[2].x, locB[2].y);
    o4[8] = make_float4(locB[2].z, locC[2].x, locC[2].y, locC[2].z);
}

// ---- Fallback: sequential one-thread-per-chain (general sizes) ----
__global__ void nerf_seq_kernel(const float* __restrict__ phi,
                                const float* __restrict__ psi,
                                const float* __restrict__ omega,
                                float* __restrict__ out,
                                int B, int L, int steps){
    int b = blockIdx.x * blockDim.x + threadIdx.x;
    if (b >= B) return;
    V3 A  = {NIX, NIY, NIZ};
    V3 Bv = {CAX, CAY, CAZ};
    V3 C  = {CIX, CIY, CIZ};
    float* o = out + (size_t)b * 9u * (size_t)(steps + 1);
    o[0]=A.x;  o[1]=A.y;  o[2]=A.z;
    o[3]=Bv.x; o[4]=Bv.y; o[5]=Bv.z;
    o[6]=C.x;  o[7]=C.y;  o[8]=C.z;
    const float* pphi = phi   + (size_t)b * L;
    const float* ppsi = psi   + (size_t)b * L;
    const float* pome = omega + (size_t)b * L;
    for (int s = 0; s < steps; ++s){
        step3(A, Bv, C, ppsi[s], pome[s], pphi[s + 1]);
        float* os = o + 9u * (size_t)(s + 1);
        os[0]=A.x;  os[1]=A.y;  os[2]=A.z;
        os[3]=Bv.x; os[4]=Bv.y; os[5]=Bv.z;
        os[6]=C.x;  os[7]=C.y;  os[8]=C.z;
    }
}

extern "C" void kernel_launch(void* const* d_in, const int* in_sizes, int n_in,
                              void* d_out, int out_size, void* d_ws, size_t ws_size,
                              hipStream_t stream) {
    const float* phi   = (const float*)d_in[0];
    const float* psi   = (const float*)d_in[1];
    const float* omega = (const float*)d_in[2];
    float* out = (float*)d_out;

    const int L = 512;
    int B = in_sizes[0] / L;
    int steps = out_size / (9 * B) - 1;

    if (steps == 511 && in_sizes[0] == B * 512) {
        nerf_direct2<<<B, 128, 0, stream>>>(phi, psi, omega, out, steps);
    } else {
        int block = 64;
        int grid = (B + block - 1) / block;
        nerf_seq_kernel<<<grid, block, 0, stream>>>(phi, psi, omega, out, B, L, steps);
    }
}

// Round 14
// 34.628 us; speedup vs baseline: 1.3111x; 1.0858x over previous
//
#include <hip/hip_runtime.h>

// NeRF backbone builder — R10 proven base (2 waves/chain, S=4, step3 math,
// per-wave scan + wc handoff, transform-pass3, full-LDS stage + coalesced
// flush) with the staging path upgraded using R12/R13-proven pieces:
//   - shifted-window packing (R13): thread tid owns rows 4tid..4tid+3 =
//     neighbor's last row (shfl_up) + own rows -> 9 ALIGNED float4s, all from
//     named registers (no runtime-indexed arrays — R11/R12 scratch lesson).
//   - vectorized staging (R12): 9 ds_write_b128 via float4-granular XOR
//     swizzle (involution, same mapping as the proven flush read).

struct V3 { float x, y, z; };

__device__ __forceinline__ V3 vsub(V3 a, V3 b){ return {a.x-b.x, a.y-b.y, a.z-b.z}; }
__device__ __forceinline__ V3 vcross(V3 a, V3 b){
    return {a.y*b.z - a.z*b.y, a.z*b.x - a.x*b.z, a.x*b.y - a.y*b.x};
}
__device__ __forceinline__ float vdot(V3 a, V3 b){ return a.x*b.x + a.y*b.y + a.z*b.z; }
__device__ __forceinline__ V3 vunit(V3 a){
    float r = rsqrtf(vdot(a,a));
    return {a.x*r, a.y*r, a.z*r};
}

struct Xform { V3 c0, c1, c2, t; };  // p' = c0*px + c1*py + c2*pz + t

__device__ __forceinline__ V3 xrot(const Xform& X, V3 p){
    return { X.c0.x*p.x + X.c1.x*p.y + X.c2.x*p.z,
             X.c0.y*p.x + X.c1.y*p.y + X.c2.y*p.z,
             X.c0.z*p.x + X.c1.z*p.y + X.c2.z*p.z };
}
__device__ __forceinline__ V3 xapply(const Xform& X, V3 p){
    V3 r = xrot(X, p);
    return { r.x + X.t.x, r.y + X.t.y, r.z + X.t.z };
}
__device__ __forceinline__ Xform xcompose(const Xform& A, const Xform& B){ // A∘B (B first)
    Xform R;
    R.c0 = xrot(A, B.c0);
    R.c1 = xrot(A, B.c1);
    R.c2 = xrot(A, B.c2);
    R.t  = xapply(A, B.t);
    return R;
}

__device__ __forceinline__ Xform frame_of(V3 A, V3 B, V3 C){
    V3 bc  = vunit(vsub(C, B));
    V3 n   = vunit(vcross(vsub(B, A), bc));
    V3 nbc = vcross(n, bc);
    return { bc, nbc, n, C };
}

__device__ __forceinline__ Xform shfl_up_xf(const Xform& X, int d){
    Xform R;
    R.c0.x = __shfl_up(X.c0.x, d); R.c0.y = __shfl_up(X.c0.y, d); R.c0.z = __shfl_up(X.c0.z, d);
    R.c1.x = __shfl_up(X.c1.x, d); R.c1.y = __shfl_up(X.c1.y, d); R.c1.z = __shfl_up(X.c1.z, d);
    R.c2.x = __shfl_up(X.c2.x, d); R.c2.y = __shfl_up(X.c2.y, d); R.c2.z = __shfl_up(X.c2.z, d);
    R.t.x  = __shfl_up(X.t.x,  d); R.t.y  = __shfl_up(X.t.y,  d); R.t.z  = __shfl_up(X.t.z,  d);
    return R;
}

// Bond constants: d0 = -L*cos(theta), Ls = L*sin(theta)
#define D0_CN   0.56630847f
#define LS_CN   1.21445243f
#define D0_NCA  0.75195559f
#define LS_NCA  1.25146426f
#define D0_CAC  0.50137496f
#define LS_CAC  1.45609861f

// Canonical incoming triple in its own frame (HW-validated R2..R13)
#define A0X (-2.0153295f)
#define A0Y ( 1.3804571f)

// World init triple
#define NIX 17.047f
#define NIY 14.099f
#define NIZ  3.625f
#define CAX 16.967f
#define CAY 12.784f
#define CAZ  4.338f
#define CIX 15.685f
#define CIY 12.755f
#define CIZ  5.133f

__device__ __forceinline__ V3 place_dihedral(V3 a, V3 b, V3 c,
                                             float d0, float Ls, float tor){
    V3 ab = vsub(b, a);
    V3 bc = vunit(vsub(c, b));
    V3 n  = vunit(vcross(ab, bc));
    V3 nbc = vcross(n, bc);
    float sn, cs;
    __sincosf(tor, &sn, &cs);
    float d1 = Ls * cs;
    float d2 = Ls * sn;
    return { c.x + d0*bc.x + d1*nbc.x + d2*n.x,
             c.y + d0*bc.y + d1*nbc.y + d2*n.y,
             c.z + d0*bc.z + d1*nbc.z + d2*n.z };
}

__device__ __forceinline__ void step3(V3& A, V3& B, V3& C,
                                      float tpsi, float tome, float tphi){
    V3 dn  = place_dihedral(A, B, C,  D0_CN,  LS_CN,  tpsi);
    V3 dca = place_dihedral(B, C, dn, D0_NCA, LS_NCA, tome);
    V3 dc  = place_dihedral(C, dn, dca, D0_CAC, LS_CAC, tphi);
    A = dn; B = dca; C = dc;
}

// float4-granular XOR swizzle (involution) — proven R10/R12 write<->read pair.
__device__ __forceinline__ void put4(float4* lds4, int p, float4 v){
    lds4[p ^ ((p >> 6) & 7)] = v;
}

// ---- Fused kernel (steps==511, L==512): 2 waves/chain, S=4 ----
__global__ __launch_bounds__(128, 4)
void nerf_vstage(const float* __restrict__ phi,
                 const float* __restrict__ psi,
                 const float* __restrict__ omega,
                 float* __restrict__ out,
                 int steps){
    const int L = 512;
    int b   = blockIdx.x;
    int tid = threadIdx.x;
    int w   = tid >> 6;                 // wave 0 / 1
    int k   = tid & 63;                 // lane in wave

    __shared__ float4 lds4[1152];       // full chain, swizzled (18432 B)
    __shared__ float wc[12];            // wave0 total transform handoff

    const float* pphi = phi   + (size_t)b * L;
    const float* ppsi = psi   + (size_t)b * L;
    const float* pome = omega + (size_t)b * L;

    int s0 = tid << 2;                  // first step of this chunk

    float4 ps = *(const float4*)(ppsi + s0);
    float4 om = *(const float4*)(pome + s0);
    float4 ph = *(const float4*)(pphi + s0);
    float phn = __shfl_down(ph.x, 1);               // phi[s0+4] from lane k+1
    if (k == 63) phn = (w == 0) ? pphi[256] : 0.f;  // w1 k63 s3 is masked anyway
    float tpsi[4] = {ps.x, ps.y, ps.z, ps.w};
    float tome[4] = {om.x, om.y, om.z, om.w};
    float tphi[4] = {ph.y, ph.z, ph.w, phn};

    // ---- pass 1: chunk atoms in LOCAL coords (statically unrolled regs) ----
    V3 A, Bv, C;
    if (tid == 0){
        A = {NIX, NIY, NIZ}; Bv = {CAX, CAY, CAZ}; C = {CIX, CIY, CIZ};
    } else {
        A = {A0X, A0Y, 0.f}; Bv = {-1.54f, 0.f, 0.f}; C = {0.f, 0.f, 0.f};
    }
    V3 locA[4], locB[4], locC[4];
    #pragma unroll
    for (int s = 0; s < 4; ++s){
        if (s0 + s < steps)
            step3(A, Bv, C, tpsi[s], tome[s], tphi[s]);
        locA[s] = A; locB[s] = Bv; locC[s] = C;   // masked slots: dup, unused
    }
    Xform V = frame_of(A, Bv, C);

    // ---- per-wave inclusive scan (proven R8/R10/R13) ----
    #pragma unroll
    for (int d = 1; d < 64; d <<= 1){
        Xform Pr = shfl_up_xf(V, d);
        if (k >= d) V = xcompose(Pr, V);
    }
    Xform Vp = shfl_up_xf(V, 1);        // wave-local prefix through lane k-1

    if (w == 0 && k == 63){             // publish wave0 total (through step 255)
        wc[0]=V.c0.x; wc[1]=V.c0.y; wc[2]=V.c0.z;
        wc[3]=V.c1.x; wc[4]=V.c1.y; wc[5]=V.c1.z;
        wc[6]=V.c2.x; wc[7]=V.c2.y; wc[8]=V.c2.z;
        wc[9]=V.t.x;  wc[10]=V.t.y; wc[11]=V.t.z;
    }
    __syncthreads();

    Xform Wc;
    Wc.c0 = {wc[0],wc[1],wc[2]};
    Wc.c1 = {wc[3],wc[4],wc[5]};
    Wc.c2 = {wc[6],wc[7],wc[8]};
    Wc.t  = {wc[9],wc[10],wc[11]};

    // ---- pass 3: transform local atoms to world IN PLACE (proven R9/R10/R13) ----
    if (tid != 0){
        Xform W;
        if (w == 0)      W = Vp;
        else if (k == 0) W = Wc;
        else             W = xcompose(Wc, Vp);
        #pragma unroll
        for (int s = 0; s < 4; ++s){
            locA[s] = xapply(W, locA[s]);
            locB[s] = xapply(W, locB[s]);
            locC[s] = xapply(W, locC[s]);
        }
    }

    // ---- neighbor row (shifted window, proven R13): row 4*tid ----
    V3 nA, nB, nC;
    nA.x = __shfl_up(locA[3].x, 1); nA.y = __shfl_up(locA[3].y, 1); nA.z = __shfl_up(locA[3].z, 1);
    nB.x = __shfl_up(locB[3].x, 1); nB.y = __shfl_up(locB[3].y, 1); nB.z = __shfl_up(locB[3].z, 1);
    nC.x = __shfl_up(locC[3].x, 1); nC.y = __shfl_up(locC[3].y, 1); nC.z = __shfl_up(locC[3].z, 1);
    if (tid == 0){                      // row 0 = init triple
        nA = {NIX, NIY, NIZ}; nB = {CAX, CAY, CAZ}; nC = {CIX, CIY, CIZ};
    } else if (k == 0){                 // tid==64: row 256 from Wc (proven R8/R13)
        nA = xapply(Wc, {A0X, A0Y, 0.f});
        nB = xapply(Wc, {-1.54f, 0.f, 0.f});
        nC = Wc.t;
    }

    // ---- vectorized staging: rows 4tid..4tid+3 = 9 float4 (R13 packing,
    //      R12 put4 swizzle), all from named registers ----
    int p = 9 * tid;
    put4(lds4, p+0, make_float4(nA.x, nA.y, nA.z, nB.x));
    put4(lds4, p+1, make_float4(nB.y, nB.z, nC.x, nC.y));
    put4(lds4, p+2, make_float4(nC.z, locA[0].x, locA[0].y, locA[0].z));
    put4(lds4, p+3, make_float4(locB[0].x, locB[0].y, locB[0].z, locC[0].x));
    put4(lds4, p+4, make_float4(locC[0].y, locC[0].z, locA[1].x, locA[1].y));
    put4(lds4, p+5, make_float4(locA[1].z, locB[1].x, locB[1].y, locB[1].z));
    put4(lds4, p+6, make_float4(locC[1].x, locC[1].y, locC[1].z, locA[2].x));
    put4(lds4, p+7, make_float4(locA[2].y, locA[2].z, locB[2].x, locB[2].y));
    put4(lds4, p+8, make_float4(locB[2].z, locC[2].x, locC[2].y, locC[2].z));
    __syncthreads();

    // ---- flush: 1152 float4, 128 threads x 9 iters, coalesced (proven R10) ----
    float4* o4 = (float4*)(out + (size_t)b * 4608u);
    #pragma unroll
    for (int i = 0; i < 9; ++i){
        int q = i * 128 + tid;
        o4[q] = lds4[q ^ ((q >> 6) & 7)];
    }
}

// ---- Fallback: sequential one-thread-per-chain (general sizes) ----
__global__ void nerf_seq_kernel(const float* __restrict__ phi,
                                const float* __restrict__ psi,
                                const float* __restrict__ omega,
                                float* __restrict__ out,
                                int B, int L, int steps){
    int b = blockIdx.x * blockDim.x + threadIdx.x;
    if (b >= B) return;
    V3 A  = {NIX, NIY, NIZ};
    V3 Bv = {CAX, CAY, CAZ};
    V3 C  = {CIX, CIY, CIZ};
    float* o = out + (size_t)b * 9u * (size_t)(steps + 1);
    o[0]=A.x;  o[1]=A.y;  o[2]=A.z;
    o[3]=Bv.x; o[4]=Bv.y; o[5]=Bv.z;
    o[6]=C.x;  o[7]=C.y;  o[8]=C.z;
    const float* pphi = phi   + (size_t)b * L;
    const float* ppsi = psi   + (size_t)b * L;
    const float* pome = omega + (size_t)b * L;
    for (int s = 0; s < steps; ++s){
        step3(A, Bv, C, ppsi[s], pome[s], pphi[s + 1]);
        float* os = o + 9u * (size_t)(s + 1);
        os[0]=A.x;  os[1]=A.y;  os[2]=A.z;
        os[3]=Bv.x; os[4]=Bv.y; os[5]=Bv.z;
        os[6]=C.x;  os[7]=C.y;  os[8]=C.z;
    }
}

extern "C" void kernel_launch(void* const* d_in, const int* in_sizes, int n_in,
                              void* d_out, int out_size, void* d_ws, size_t ws_size,
                              hipStream_t stream) {
    const float* phi   = (const float*)d_in[0];
    const float* psi   = (const float*)d_in[1];
    const float* omega = (const float*)d_in[2];
    float* out = (float*)d_out;

    const int L = 512;
    int B = in_sizes[0] / L;
    int steps = out_size / (9 * B) - 1;

    if (steps == 511 && in_sizes[0] == B * 512) {
        nerf_vstage<<<B, 128, 0, stream>>>(phi, psi, omega, out, steps);
    } else {
        int block = 64;
        int grid = (B + block - 1) / block;
        nerf_seq_kernel<<<grid, block, 0, stream>>>(phi, psi, omega, out, B, L, steps);
    }
}

// Round 15
// 30.847 us; speedup vs baseline: 1.4718x; 1.1226x over previous
//
#include <hip/hip_runtime.h>

// NeRF backbone builder — R12 structure (correctness-proven), ONE change:
// __launch_bounds__(64,4) -> __launch_bounds__(64). R12's 45µs was a VGPR
// spill (cap 128 < ~150 need at S=8: measured VGPR=64, FETCH 34MB scratch).
// Structure: 1 wave/chain, S=8, half-LDS staging (9216B) via shifted-window
// (lanes 0-31 own rows 0-255 exactly), transform-pass3, put4-vectorized
// staging, coalesced flush. Proven step3 math only.

struct V3 { float x, y, z; };

__device__ __forceinline__ V3 vsub(V3 a, V3 b){ return {a.x-b.x, a.y-b.y, a.z-b.z}; }
__device__ __forceinline__ V3 vcross(V3 a, V3 b){
    return {a.y*b.z - a.z*b.y, a.z*b.x - a.x*b.z, a.x*b.y - a.y*b.x};
}
__device__ __forceinline__ float vdot(V3 a, V3 b){ return a.x*b.x + a.y*b.y + a.z*b.z; }
__device__ __forceinline__ V3 vunit(V3 a){
    float r = rsqrtf(vdot(a,a));
    return {a.x*r, a.y*r, a.z*r};
}

struct Xform { V3 c0, c1, c2, t; };  // p' = c0*px + c1*py + c2*pz + t

__device__ __forceinline__ V3 xrot(const Xform& X, V3 p){
    return { X.c0.x*p.x + X.c1.x*p.y + X.c2.x*p.z,
             X.c0.y*p.x + X.c1.y*p.y + X.c2.y*p.z,
             X.c0.z*p.x + X.c1.z*p.y + X.c2.z*p.z };
}
__device__ __forceinline__ V3 xapply(const Xform& X, V3 p){
    V3 r = xrot(X, p);
    return { r.x + X.t.x, r.y + X.t.y, r.z + X.t.z };
}
__device__ __forceinline__ Xform xcompose(const Xform& A, const Xform& B){ // A∘B (B first)
    Xform R;
    R.c0 = xrot(A, B.c0);
    R.c1 = xrot(A, B.c1);
    R.c2 = xrot(A, B.c2);
    R.t  = xapply(A, B.t);
    return R;
}

__device__ __forceinline__ Xform frame_of(V3 A, V3 B, V3 C){
    V3 bc  = vunit(vsub(C, B));
    V3 n   = vunit(vcross(vsub(B, A), bc));
    V3 nbc = vcross(n, bc);
    return { bc, nbc, n, C };
}

__device__ __forceinline__ Xform shfl_up_xf(const Xform& X, int d){
    Xform R;
    R.c0.x = __shfl_up(X.c0.x, d); R.c0.y = __shfl_up(X.c0.y, d); R.c0.z = __shfl_up(X.c0.z, d);
    R.c1.x = __shfl_up(X.c1.x, d); R.c1.y = __shfl_up(X.c1.y, d); R.c1.z = __shfl_up(X.c1.z, d);
    R.c2.x = __shfl_up(X.c2.x, d); R.c2.y = __shfl_up(X.c2.y, d); R.c2.z = __shfl_up(X.c2.z, d);
    R.t.x  = __shfl_up(X.t.x,  d); R.t.y  = __shfl_up(X.t.y,  d); R.t.z  = __shfl_up(X.t.z,  d);
    return R;
}

// Bond constants: d0 = -L*cos(theta), Ls = L*sin(theta)
#define D0_CN   0.56630847f
#define LS_CN   1.21445243f
#define D0_NCA  0.75195559f
#define LS_NCA  1.25146426f
#define D0_CAC  0.50137496f
#define LS_CAC  1.45609861f

// Canonical incoming triple in its own frame (HW-validated R2..R14)
#define A0X (-2.0153295f)
#define A0Y ( 1.3804571f)

// World init triple
#define NIX 17.047f
#define NIY 14.099f
#define NIZ  3.625f
#define CAX 16.967f
#define CAY 12.784f
#define CAZ  4.338f
#define CIX 15.685f
#define CIY 12.755f
#define CIZ  5.133f

__device__ __forceinline__ V3 place_dihedral(V3 a, V3 b, V3 c,
                                             float d0, float Ls, float tor){
    V3 ab = vsub(b, a);
    V3 bc = vunit(vsub(c, b));
    V3 n  = vunit(vcross(ab, bc));
    V3 nbc = vcross(n, bc);
    float sn, cs;
    __sincosf(tor, &sn, &cs);
    float d1 = Ls * cs;
    float d2 = Ls * sn;
    return { c.x + d0*bc.x + d1*nbc.x + d2*n.x,
             c.y + d0*bc.y + d1*nbc.y + d2*n.y,
             c.z + d0*bc.z + d1*nbc.z + d2*n.z };
}

__device__ __forceinline__ void step3(V3& A, V3& B, V3& C,
                                      float tpsi, float tome, float tphi){
    V3 dn  = place_dihedral(A, B, C,  D0_CN,  LS_CN,  tpsi);
    V3 dca = place_dihedral(B, C, dn, D0_NCA, LS_NCA, tome);
    V3 dc  = place_dihedral(C, dn, dca, D0_CAC, LS_CAC, tphi);
    A = dn; B = dca; C = dc;
}

// float4-granular XOR swizzle (involution) — proven R10/R12/R14 pair.
__device__ __forceinline__ void put4(float4* lds4, int p, float4 v){
    lds4[p ^ ((p >> 6) & 7)] = v;
}

// Stage 4 rows (36 floats = 9 float4) starting at float4 index p.
__device__ __forceinline__ void stage36(float4* lds4, int p,
    V3 aA, V3 aB, V3 aC, V3 bA, V3 bB, V3 bC,
    V3 cA, V3 cB, V3 cC, V3 dA, V3 dB, V3 dC){
    put4(lds4, p+0, make_float4(aA.x, aA.y, aA.z, aB.x));
    put4(lds4, p+1, make_float4(aB.y, aB.z, aC.x, aC.y));
    put4(lds4, p+2, make_float4(aC.z, bA.x, bA.y, bA.z));
    put4(lds4, p+3, make_float4(bB.x, bB.y, bB.z, bC.x));
    put4(lds4, p+4, make_float4(bC.y, bC.z, cA.x, cA.y));
    put4(lds4, p+5, make_float4(cA.z, cB.x, cB.y, cB.z));
    put4(lds4, p+6, make_float4(cC.x, cC.y, cC.z, dA.x));
    put4(lds4, p+7, make_float4(dA.y, dA.z, dB.x, dB.y));
    put4(lds4, p+8, make_float4(dB.z, dC.x, dC.y, dC.z));
}

// ---- Fused kernel: one wave per chain, half-LDS staging ----
__global__ __launch_bounds__(64)
void nerf_half(const float* __restrict__ phi,
               const float* __restrict__ psi,
               const float* __restrict__ omega,
               float* __restrict__ out,
               int steps){
    const int L = 512;
    int b = blockIdx.x;
    int k = threadIdx.x;              // chunk id 0..63
    int s0 = k * 8;

    __shared__ float4 lds4[576];      // 9216 B = half chain

    const float* pphi = phi   + (size_t)b * L;
    const float* ppsi = psi   + (size_t)b * L;
    const float* pome = omega + (size_t)b * L;

    float4 ps0 = ((const float4*)(ppsi + s0))[0];
    float4 ps1 = ((const float4*)(ppsi + s0))[1];
    float4 om0 = ((const float4*)(pome + s0))[0];
    float4 om1 = ((const float4*)(pome + s0))[1];
    float4 ph0 = ((const float4*)(pphi + s0))[0];
    float4 ph1 = ((const float4*)(pphi + s0))[1];
    float phi8 = __shfl_down(ph0.x, 1);   // phi[s0+8] from lane k+1 (unused at k=63)

    float tpsi[8] = {ps0.x, ps0.y, ps0.z, ps0.w, ps1.x, ps1.y, ps1.z, ps1.w};
    float tome[8] = {om0.x, om0.y, om0.z, om0.w, om1.x, om1.y, om1.z, om1.w};
    float tphi[8] = {ph0.y, ph0.z, ph0.w, ph1.x, ph1.y, ph1.z, ph1.w, phi8};

    // Pass 1: local chunk atoms in registers (R9-proven).
    V3 A, Bv, C;
    if (k == 0){
        A = {NIX, NIY, NIZ}; Bv = {CAX, CAY, CAZ}; C = {CIX, CIY, CIZ};
    } else {
        A = {A0X, A0Y, 0.f}; Bv = {-1.54f, 0.f, 0.f}; C = {0.f, 0.f, 0.f};
    }
    V3 locA[8], locB[8], locC[8];
    #pragma unroll
    for (int s = 0; s < 8; ++s){
        if (s0 + s < steps)
            step3(A, Bv, C, tpsi[s], tome[s], tphi[s]);
        locA[s] = A; locB[s] = Bv; locC[s] = C;   // k63 s7: dup, never staged
    }
    Xform V = frame_of(A, Bv, C);

    // Pass 2: in-wave inclusive scan (proven R2..R14).
    #pragma unroll
    for (int d = 1; d < 64; d <<= 1){
        Xform Pr = shfl_up_xf(V, d);
        if (k >= d) V = xcompose(Pr, V);
    }
    Xform Wp = shfl_up_xf(V, 1);      // W_{k-1} at lane k (lane 0 unused)

    // Pass 3: transform local atoms to world IN PLACE (R9-proven math).
    if (k != 0){
        #pragma unroll
        for (int s = 0; s < 8; ++s){
            locA[s] = xapply(Wp, locA[s]);
            locB[s] = xapply(Wp, locB[s]);
            locC[s] = xapply(Wp, locC[s]);
        }
    }

    // Neighbor row (shifted window): lane k's output rows are 8k..8k+7 =
    // lane k-1's last row (global row 8k) + own steps s=0..6 (rows 8k+1..8k+7).
    V3 nA, nB, nC;
    nA.x = __shfl_up(locA[7].x, 1); nA.y = __shfl_up(locA[7].y, 1); nA.z = __shfl_up(locA[7].z, 1);
    nB.x = __shfl_up(locB[7].x, 1); nB.y = __shfl_up(locB[7].y, 1); nB.z = __shfl_up(locB[7].z, 1);
    nC.x = __shfl_up(locC[7].x, 1); nC.y = __shfl_up(locC[7].y, 1); nC.z = __shfl_up(locC[7].z, 1);
    if (k == 0){                       // row 0 = init triple
        nA = {NIX, NIY, NIZ}; nB = {CAX, CAY, CAZ}; nC = {CIX, CIY, CIZ};
    }

    int m = k & 31;                    // lane offset within half
    int p0 = 18 * m;                   // float4 base within half buffer
    float4* o4 = (float4*)(out + (size_t)b * 4608u);

    // Half 0: lanes 0..31 stage rows 0..255, whole wave flushes.
    if (k < 32){
        stage36(lds4, p0,     nA, nB, nC, locA[0], locB[0], locC[0],
                              locA[1], locB[1], locC[1], locA[2], locB[2], locC[2]);
        stage36(lds4, p0 + 9, locA[3], locB[3], locC[3], locA[4], locB[4], locC[4],
                              locA[5], locB[5], locC[5], locA[6], locB[6], locC[6]);
    }
    __syncthreads();
    #pragma unroll
    for (int i = 0; i < 9; ++i){
        int q = i * 64 + k;
        o4[q] = lds4[q ^ ((q >> 6) & 7)];
    }
    __syncthreads();

    // Half 1: lanes 32..63 stage rows 256..511, whole wave flushes.
    if (k >= 32){
        stage36(lds4, p0,     nA, nB, nC, locA[0], locB[0], locC[0],
                              locA[1], locB[1], locC[1], locA[2], locB[2], locC[2]);
        stage36(lds4, p0 + 9, locA[3], locB[3], locC[3], locA[4], locB[4], locC[4],
                              locA[5], locB[5], locC[5], locA[6], locB[6], locC[6]);
    }
    __syncthreads();
    #pragma unroll
    for (int i = 0; i < 9; ++i){
        int q = i * 64 + k;
        o4[576 + q] = lds4[q ^ ((q >> 6) & 7)];
    }
}

// ---- Fallback: sequential one-thread-per-chain (general sizes) ----
__global__ void nerf_seq_kernel(const float* __restrict__ phi,
                                const float* __restrict__ psi,
                                const float* __restrict__ omega,
                                float* __restrict__ out,
                                int B, int L, int steps){
    int b = blockIdx.x * blockDim.x + threadIdx.x;
    if (b >= B) return;
    V3 A  = {NIX, NIY, NIZ};
    V3 Bv = {CAX, CAY, CAZ};
    V3 C  = {CIX, CIY, CIZ};
    float* o = out + (size_t)b * 9u * (size_t)(steps + 1);
    o[0]=A.x;  o[1]=A.y;  o[2]=A.z;
    o[3]=Bv.x; o[4]=Bv.y; o[5]=Bv.z;
    o[6]=C.x;  o[7]=C.y;  o[8]=C.z;
    const float* pphi = phi   + (size_t)b * L;
    const float* ppsi = psi   + (size_t)b * L;
    const float* pome = omega + (size_t)b * L;
    for (int s = 0; s < steps; ++s){
        step3(A, Bv, C, ppsi[s], pome[s], pphi[s + 1]);
        float* os = o + 9u * (size_t)(s + 1);
        os[0]=A.x;  os[1]=A.y;  os[2]=A.z;
        os[3]=Bv.x; os[4]=Bv.y; os[5]=Bv.z;
        os[6]=C.x;  os[7]=C.y;  os[8]=C.z;
    }
}

extern "C" void kernel_launch(void* const* d_in, const int* in_sizes, int n_in,
                              void* d_out, int out_size, void* d_ws, size_t ws_size,
                              hipStream_t stream) {
    const float* phi   = (const float*)d_in[0];
    const float* psi   = (const float*)d_in[1];
    const float* omega = (const float*)d_in[2];
    float* out = (float*)d_out;

    const int L = 512;
    int B = in_sizes[0] / L;
    int steps = out_size / (9 * B) - 1;

    if (steps == 511 && in_sizes[0] == B * 512) {
        nerf_half<<<B, 64, 0, stream>>>(phi, psi, omega, out, steps);
    } else {
        int block = 64;
        int grid = (B + block - 1) / block;
        nerf_seq_kernel<<<grid, block, 0, stream>>>(phi, psi, omega, out, B, L, steps);
    }
}